// Round 1
// baseline (4866.261 us; speedup 1.0000x reference)
//
#include <hip/hip_runtime.h>
#include <hip/hip_bf16.h>
#include <math.h>

#define BB 4
#define SS 2048
#define HIDDEN 2048
#define NHEADS 16
#define HDIM 128
#define BSROWS (BB * SS)
#define ATT_SCALE 0.08838834764831845f

static __device__ __forceinline__ unsigned encf(float x) {
  unsigned b = __float_as_uint(x);
  return (b & 0x80000000u) ? ~b : (b | 0x80000000u);
}
static __device__ __forceinline__ float decf(unsigned k) {
  unsigned b = (k & 0x80000000u) ? (k ^ 0x80000000u) : ~k;
  return __uint_as_float(b);
}
static __device__ __forceinline__ float sigf(float x) {
  return 1.0f / (1.0f + expf(-x));
}

// cos/sin tables, (S x 64) each (table duplicates across halves in reference)
__global__ void rope_tables_k(float* __restrict__ ct, float* __restrict__ st) {
  int t = blockIdx.x;
  int d = threadIdx.x;  // 0..63
  float inv = powf(10000.0f, -(float)d * (1.0f / 64.0f));
  float a = (float)t * inv;
  ct[t * 64 + d] = cosf(a);
  st[t * 64 + d] = sinf(a);
}

// M = compress^T @ decompress^T : M[a][c] = sum_m cw[m*128+a] * dw[c*32+m]
__global__ void build_m_k(const float* __restrict__ kc, const float* __restrict__ kdw,
                          const float* __restrict__ vc, const float* __restrict__ vdw,
                          float* __restrict__ mk, float* __restrict__ mv) {
  int a = blockIdx.x;
  int c = threadIdx.x;  // 128 threads
  const float* cw = blockIdx.y ? vc : kc;
  const float* dw = blockIdx.y ? vdw : kdw;
  float* m = blockIdx.y ? mv : mk;
  float acc = 0.f;
#pragma unroll
  for (int mm = 0; mm < 32; mm++) acc += cw[mm * 128 + a] * dw[c * 32 + mm];
  m[a * 128 + c] = acc;
}

__global__ void mm_init_k(unsigned* mmx) {
  int i = threadIdx.x;
  if (i < 4) mmx[i] = (i & 1) ? 0u : 0xFFFFFFFFu;  // even: min-slot, odd: max-slot
}

// C[m,n] = sum_k A[m,k] * B[n,k]   (A: MxK rm, B: NxK rm, C: MxN rm)
// block 256 threads, tile 128x128, BK=16, 8x8 micro
__global__ __launch_bounds__(256) void gemm_nt_k(const float* __restrict__ A,
                                                 const float* __restrict__ Bm,
                                                 float* __restrict__ C,
                                                 int M, int N, int K) {
  __shared__ float As[16 * 132];
  __shared__ float Bs[16 * 132];
  int tid = threadIdx.x;
  int tx = tid & 15, ty = tid >> 4;
  int m0 = blockIdx.y * 128, n0 = blockIdx.x * 128;
  int lr = tid >> 1, lc = (tid & 1) * 8;
  const float* Ap = A + (long)(m0 + lr) * K + lc;
  const float* Bp = Bm + (long)(n0 + lr) * K + lc;
  float acc[8][8];
#pragma unroll
  for (int i = 0; i < 8; i++)
#pragma unroll
    for (int j = 0; j < 8; j++) acc[i][j] = 0.f;

  for (int k0 = 0; k0 < K; k0 += 16) {
    float4 a0 = *(const float4*)(Ap + k0);
    float4 a1 = *(const float4*)(Ap + k0 + 4);
    float4 b0 = *(const float4*)(Bp + k0);
    float4 b1 = *(const float4*)(Bp + k0 + 4);
    As[(lc + 0) * 132 + lr] = a0.x;
    As[(lc + 1) * 132 + lr] = a0.y;
    As[(lc + 2) * 132 + lr] = a0.z;
    As[(lc + 3) * 132 + lr] = a0.w;
    As[(lc + 4) * 132 + lr] = a1.x;
    As[(lc + 5) * 132 + lr] = a1.y;
    As[(lc + 6) * 132 + lr] = a1.z;
    As[(lc + 7) * 132 + lr] = a1.w;
    Bs[(lc + 0) * 132 + lr] = b0.x;
    Bs[(lc + 1) * 132 + lr] = b0.y;
    Bs[(lc + 2) * 132 + lr] = b0.z;
    Bs[(lc + 3) * 132 + lr] = b0.w;
    Bs[(lc + 4) * 132 + lr] = b1.x;
    Bs[(lc + 5) * 132 + lr] = b1.y;
    Bs[(lc + 6) * 132 + lr] = b1.z;
    Bs[(lc + 7) * 132 + lr] = b1.w;
    __syncthreads();
#pragma unroll
    for (int kk = 0; kk < 16; kk++) {
      float4 aa0 = *(const float4*)&As[kk * 132 + ty * 4];
      float4 aa1 = *(const float4*)&As[kk * 132 + 64 + ty * 4];
      float4 bb0 = *(const float4*)&Bs[kk * 132 + tx * 4];
      float4 bb1 = *(const float4*)&Bs[kk * 132 + 64 + tx * 4];
      float av[8] = {aa0.x, aa0.y, aa0.z, aa0.w, aa1.x, aa1.y, aa1.z, aa1.w};
      float bv[8] = {bb0.x, bb0.y, bb0.z, bb0.w, bb1.x, bb1.y, bb1.z, bb1.w};
#pragma unroll
      for (int i = 0; i < 8; i++)
#pragma unroll
        for (int j = 0; j < 8; j++) acc[i][j] += av[i] * bv[j];
    }
    __syncthreads();
  }
#pragma unroll
  for (int i = 0; i < 8; i++) {
    int r = m0 + ((i < 4) ? (ty * 4 + i) : (64 + ty * 4 + (i - 4)));
    float* cp = C + (long)r * N + n0;
    float4 o0 = make_float4(acc[i][0], acc[i][1], acc[i][2], acc[i][3]);
    float4 o1 = make_float4(acc[i][4], acc[i][5], acc[i][6], acc[i][7]);
    *(float4*)(cp + tx * 4) = o0;
    *(float4*)(cp + 64 + tx * 4) = o1;
  }
}

// in-place RoPE; each thread owns pair (j, j+64) of one (row, head)
__global__ void rope_apply_k(float* buf, const float* __restrict__ ct,
                             const float* __restrict__ st, int heads, int total) {
  int idx = blockIdx.x * 256 + threadIdx.x;
  if (idx >= total) return;
  int j = idx & 63;
  int hh = (idx >> 6) % heads;
  int row = idx / (64 * heads);
  int t = row & (SS - 1);
  float c = ct[t * 64 + j], s = st[t * 64 + j];
  float* p = buf + ((long)row * heads + hh) * 128;
  float x0 = p[j], x1 = p[j + 64];
  p[j] = x0 * c - x1 * s;
  p[j + 64] = x1 * c + x0 * s;
}

// row transform (in-place): buf_row <- buf_row @ M (128x128), plus global min/max
__global__ __launch_bounds__(128) void kv_transform_k(float* kb, float* vb,
                                                      const float* __restrict__ mk,
                                                      const float* __restrict__ mv,
                                                      unsigned* mmx) {
  int which = blockIdx.y;
  float* buf = which ? vb : kb;
  const float* M = which ? mv : mk;
  __shared__ float rowb[128];
  __shared__ float red[128];
  int tid = threadIdx.x;
  float vmin = 3.4e38f, vmax = -3.4e38f;
  int r0 = blockIdx.x * 128;
  for (int ri = 0; ri < 128; ri++) {
    long row = r0 + ri;
    __syncthreads();
    rowb[tid] = buf[row * 128 + tid];
    __syncthreads();
    float acc = 0.f;
#pragma unroll 8
    for (int a = 0; a < 128; a++) acc += rowb[a] * M[a * 128 + tid];
    buf[row * 128 + tid] = acc;
    vmin = fminf(vmin, acc);
    vmax = fmaxf(vmax, acc);
  }
  red[tid] = vmin;
  __syncthreads();
  for (int s2 = 64; s2 > 0; s2 >>= 1) {
    if (tid < s2) red[tid] = fminf(red[tid], red[tid + s2]);
    __syncthreads();
  }
  if (tid == 0) atomicMin(&mmx[which * 2 + 0], encf(red[0]));
  __syncthreads();
  red[tid] = vmax;
  __syncthreads();
  for (int s2 = 64; s2 > 0; s2 >>= 1) {
    if (tid < s2) red[tid] = fmaxf(red[tid], red[tid + s2]);
    __syncthreads();
  }
  if (tid == 0) atomicMax(&mmx[which * 2 + 1], encf(red[0]));
}

__global__ void quant_k(float* kb, float* vb, const unsigned* __restrict__ mmx) {
  int idx = blockIdx.x * 256 + threadIdx.x;  // 0 .. 2*BSROWS*HDIM-1
  int which = idx >> 20;                     // BSROWS*HDIM = 1048576 per tensor
  float* buf = which ? vb : kb;
  int i = idx & 1048575;
  float fmin = decf(mmx[which * 2 + 0]);
  float fmax = decf(mmx[which * 2 + 1]);
  float sc = (fmax - fmin) / 255.0f;
  float t = buf[i];
  float qv = rintf((t - fmin) / sc);
  qv = fminf(fmaxf(qv, 0.0f), 255.0f);
  buf[i] = qv * sc + fmin;
}

// windowed sigmoid-attention with per-row two-window blend.
// block: 256 threads, 32 query rows of one (b,h). out may alias q.
__global__ __launch_bounds__(256) void attn_k(const float* q, const float* kq,
                                              const float* vq, float* outp) {
  __shared__ float Qs[32 * 129];
  __shared__ float Ks[32 * 129];
  __shared__ float Vs[32 * 132];
  __shared__ float Ps[32 * 33];
  __shared__ float rsum[32];
  int tid = threadIdx.x;
  int b = blockIdx.y >> 4;
  int h = blockIdx.y & 15;
  int t0 = blockIdx.x * 32;
  int wa = t0 >> 8;

  for (int i = tid; i < 4096; i += 256) {
    int r = i >> 7, d = i & 127;
    Qs[r * 129 + d] = q[((long)(b * SS + t0 + r) * NHEADS + h) * HDIM + d];
  }

  int rP = tid >> 3;          // PV row 0..31
  int c0 = (tid & 7) * 16;    // PV col base
  int cS = tid & 31;          // score key col
  int rg = (tid >> 5) * 4;    // score row base
  float alpha = (float)((t0 + rP) & 255) * (1.0f / 255.0f);

  float accOut[16];
#pragma unroll
  for (int j = 0; j < 16; j++) accOut[j] = 0.f;

  for (int pass = 0; pass < 2; pass++) {
    int wsS, wsE;
    if (pass == 0) {
      if (wa == 0) continue;
      wsS = wa * 256 - 256;
      wsE = wsS + 512;
    } else {
      wsS = wa * 256;
      wsE = wsS + 512;
      if (wsE > SS) wsE = SS;
    }
    if (tid < 32) rsum[tid] = 0.f;
    float acc[16];
#pragma unroll
    for (int j = 0; j < 16; j++) acc[j] = 0.f;
    __syncthreads();
    for (int k0 = wsS; k0 < wsE; k0 += 32) {
      for (int i = tid; i < 4096; i += 256) {
        int r = i >> 7, d = i & 127;
        long grow = (long)(b * SS + k0 + r) * HDIM + d;
        Ks[r * 129 + d] = kq[grow];
        Vs[r * 132 + d] = vq[grow];
      }
      __syncthreads();
      {
        float s0 = 0.f, s1 = 0.f, s2 = 0.f, s3 = 0.f;
        const float* kp = &Ks[cS * 129];
        const float* q0 = &Qs[(rg + 0) * 129];
        const float* q1 = &Qs[(rg + 1) * 129];
        const float* q2 = &Qs[(rg + 2) * 129];
        const float* q3 = &Qs[(rg + 3) * 129];
#pragma unroll 8
        for (int kd = 0; kd < 128; kd++) {
          float kv = kp[kd];
          s0 += q0[kd] * kv;
          s1 += q1[kd] * kv;
          s2 += q2[kd] * kv;
          s3 += q3[kd] * kv;
        }
        Ps[(rg + 0) * 33 + cS] = sigf(s0 * ATT_SCALE);
        Ps[(rg + 1) * 33 + cS] = sigf(s1 * ATT_SCALE);
        Ps[(rg + 2) * 33 + cS] = sigf(s2 * ATT_SCALE);
        Ps[(rg + 3) * 33 + cS] = sigf(s3 * ATT_SCALE);
      }
      __syncthreads();
      if (tid < 32) {
        float sm = 0.f;
#pragma unroll 8
        for (int c = 0; c < 32; c++) sm += Ps[tid * 33 + c];
        rsum[tid] += sm;
      }
#pragma unroll 4
      for (int k = 0; k < 32; k++) {
        float p = Ps[rP * 33 + k];
        const float* vp = &Vs[k * 132 + c0];
        float4 v0 = *(const float4*)(vp + 0);
        float4 v1 = *(const float4*)(vp + 4);
        float4 v2 = *(const float4*)(vp + 8);
        float4 v3 = *(const float4*)(vp + 12);
        acc[0] += p * v0.x;
        acc[1] += p * v0.y;
        acc[2] += p * v0.z;
        acc[3] += p * v0.w;
        acc[4] += p * v1.x;
        acc[5] += p * v1.y;
        acc[6] += p * v1.z;
        acc[7] += p * v1.w;
        acc[8] += p * v2.x;
        acc[9] += p * v2.y;
        acc[10] += p * v2.z;
        acc[11] += p * v2.w;
        acc[12] += p * v3.x;
        acc[13] += p * v3.y;
        acc[14] += p * v3.z;
        acc[15] += p * v3.w;
      }
      __syncthreads();
    }
    float inv = 1.0f / (rsum[rP] + 1e-8f);
    float w = (pass == 0) ? (1.0f - alpha) : ((wa == 0) ? 1.0f : alpha);
#pragma unroll
    for (int j = 0; j < 16; j++) accOut[j] += w * acc[j] * inv;
    __syncthreads();
  }
#pragma unroll
  for (int j = 0; j < 16; j++)
    outp[((long)(b * SS + t0 + rP) * NHEADS + h) * HDIM + c0 + j] = accOut[j];
}

extern "C" void kernel_launch(void* const* d_in, const int* in_sizes, int n_in,
                              void* d_out, int out_size, void* d_ws, size_t ws_size,
                              hipStream_t stream) {
  const float* x = (const float*)d_in[0];
  const float* wq = (const float*)d_in[1];
  const float* wk = (const float*)d_in[2];
  const float* wv = (const float*)d_in[3];
  const float* wo = (const float*)d_in[4];
  const float* kcw = (const float*)d_in[5];
  const float* vcw = (const float*)d_in[6];
  const float* kdw = (const float*)d_in[7];
  const float* vdw = (const float*)d_in[8];
  float* out = (float*)d_out;

  float* q = (float*)d_ws;                       // BSROWS*HIDDEN      (64 MB)
  float* kb = q + (long)BSROWS * HIDDEN;         // BSROWS*HDIM        (4 MB)
  float* vb = kb + (long)BSROWS * HDIM;          // BSROWS*HDIM        (4 MB)
  float* ct = vb + (long)BSROWS * HDIM;          // S*64
  float* st = ct + SS * 64;                      // S*64
  float* mk = st + SS * 64;                      // 128*128
  float* mv = mk + 128 * 128;                    // 128*128
  unsigned* mmx = (unsigned*)(mv + 128 * 128);   // 4

  rope_tables_k<<<SS, 64, 0, stream>>>(ct, st);
  build_m_k<<<dim3(128, 2), 128, 0, stream>>>(kcw, kdw, vcw, vdw, mk, mv);

  // Q = x @ wq^T ; K = x @ wk^T ; V = x @ wv^T
  gemm_nt_k<<<dim3(HIDDEN / 128, BSROWS / 128), 256, 0, stream>>>(x, wq, q, BSROWS, HIDDEN, HIDDEN);
  gemm_nt_k<<<dim3(1, BSROWS / 128), 256, 0, stream>>>(x, wk, kb, BSROWS, HDIM, HIDDEN);
  gemm_nt_k<<<dim3(1, BSROWS / 128), 256, 0, stream>>>(x, wv, vb, BSROWS, HDIM, HIDDEN);

  // RoPE on Q (16 heads) and K (1 head); V is not roped
  rope_apply_k<<<(BSROWS * NHEADS * 64) / 256, 256, 0, stream>>>(q, ct, st, NHEADS, BSROWS * NHEADS * 64);
  rope_apply_k<<<(BSROWS * 64) / 256, 256, 0, stream>>>(kb, ct, st, 1, BSROWS * 64);

  // K/V low-rank transform + global min/max, then 8-bit quant-dequant
  mm_init_k<<<1, 64, 0, stream>>>(mmx);
  kv_transform_k<<<dim3(BSROWS / 128, 2), 128, 0, stream>>>(kb, vb, mk, mv, mmx);
  quant_k<<<(2 * BSROWS * HDIM) / 256, 256, 0, stream>>>(kb, vb, mmx);

  // windowed attention; output written in-place into q buffer
  attn_k<<<dim3(SS / 32, BB * NHEADS), 256, 0, stream>>>(q, kb, vb, q);

  // out = attn_out @ wo^T
  gemm_nt_k<<<dim3(HIDDEN / 128, BSROWS / 128), 256, 0, stream>>>(q, wo, out, BSROWS, HIDDEN, HIDDEN);
}

// Round 2
// 3624.519 us; speedup vs baseline: 1.3426x; 1.3426x over previous
//
#include <hip/hip_runtime.h>
#include <hip/hip_bf16.h>
#include <math.h>

#define BB 4
#define SS 2048
#define HIDDEN 2048
#define NHEADS 16
#define HDIM 128
#define BSROWS (BB * SS)
#define ATT_SCALE 0.08838834764831845f

typedef __attribute__((ext_vector_type(8))) short short8v;
typedef __attribute__((ext_vector_type(4))) float f32x4;

static __device__ __forceinline__ unsigned encf(float x) {
  unsigned b = __float_as_uint(x);
  return (b & 0x80000000u) ? ~b : (b | 0x80000000u);
}
static __device__ __forceinline__ float decf(unsigned k) {
  unsigned b = (k & 0x80000000u) ? (k ^ 0x80000000u) : ~k;
  return __uint_as_float(b);
}
static __device__ __forceinline__ float sigf(float x) {
  return 1.0f / (1.0f + expf(-x));
}
static __device__ __forceinline__ unsigned short f2bf(float f) {
  unsigned u = __float_as_uint(f);
  u += 0x7FFFu + ((u >> 16) & 1u);  // RNE
  return (unsigned short)(u >> 16);
}
static __device__ __forceinline__ float bf2f(unsigned short h) {
  return __uint_as_float(((unsigned)h) << 16);
}

// ---------------- small setup kernels ----------------

__global__ void rope_tables_k(float* __restrict__ ct, float* __restrict__ st) {
  int t = blockIdx.x;
  int d = threadIdx.x;  // 0..63
  float inv = powf(10000.0f, -(float)d * (1.0f / 64.0f));
  float a = (float)t * inv;
  ct[t * 64 + d] = cosf(a);
  st[t * 64 + d] = sinf(a);
}

__global__ void build_m_k(const float* __restrict__ kc, const float* __restrict__ kdw,
                          const float* __restrict__ vc, const float* __restrict__ vdw,
                          float* __restrict__ mk, float* __restrict__ mv) {
  int a = blockIdx.x;
  int c = threadIdx.x;
  const float* cw = blockIdx.y ? vc : kc;
  const float* dw = blockIdx.y ? vdw : kdw;
  float* m = blockIdx.y ? mv : mk;
  float acc = 0.f;
#pragma unroll
  for (int mm = 0; mm < 32; mm++) acc += cw[mm * 128 + a] * dw[c * 32 + mm];
  m[a * 128 + c] = acc;
}

__global__ void mm_init_k(unsigned* mmx) {
  int i = threadIdx.x;
  if (i < 4) mmx[i] = (i & 1) ? 0u : 0xFFFFFFFFu;
}

// split fp32 -> bf16 hi + bf16 lo (residual)
__global__ void split_bf16_k(const float* __restrict__ src, unsigned short* __restrict__ hi,
                             unsigned short* __restrict__ lo, int n4) {
  int i = blockIdx.x * 256 + threadIdx.x;
  int stride = gridDim.x * 256;
  for (; i < n4; i += stride) {
    float4 v = ((const float4*)src)[i];
    unsigned short h0 = f2bf(v.x), h1 = f2bf(v.y), h2 = f2bf(v.z), h3 = f2bf(v.w);
    unsigned short l0 = f2bf(v.x - bf2f(h0));
    unsigned short l1 = f2bf(v.y - bf2f(h1));
    unsigned short l2 = f2bf(v.z - bf2f(h2));
    unsigned short l3 = f2bf(v.w - bf2f(h3));
    ((ushort4*)hi)[i] = make_ushort4(h0, h1, h2, h3);
    ((ushort4*)lo)[i] = make_ushort4(l0, l1, l2, l3);
  }
}

// ---------------- bf16-split MFMA GEMM ----------------
// C[M=8192][N=2048] fp32 = sum over 3 phases: Ah.Bh^T + Ah.Bl^T + Al.Bh^T
// A* : [8192][2048] bf16 row-major, B* : [2048][2048] bf16 row-major (NT)
// block 256 thr = 4 waves (2x2 of 64x64), tile 128x128, BK=64, m97 structure.
__global__ __launch_bounds__(256) void gemm_split_mfma_k(
    const unsigned short* __restrict__ Ah, const unsigned short* __restrict__ Al,
    const unsigned short* __restrict__ Bh, const unsigned short* __restrict__ Bl,
    float* __restrict__ C) {
  const int K = 2048, N = 2048;
  __shared__ unsigned short As[128 * 64];
  __shared__ unsigned short Bs[128 * 64];
  int tid = threadIdx.x;
  int lane = tid & 63, wid = tid >> 6;
  int wr = wid >> 1, wc = wid & 1;
  int m0 = blockIdx.y * 128, n0 = blockIdx.x * 128;

  f32x4 acc[4][4] = {};

  int off_ = (wid << 10) + (lane << 4);  // byte offset base for staging
  int l15 = lane & 15, lk = lane >> 4;   // fragment row / k-group

  for (int t = 0; t < 96; ++t) {
    int ph = t >> 5;          // 0,1,2
    int kt = t & 31;
    const unsigned short* Ap = (ph == 2) ? Al : Ah;
    const unsigned short* Bp = (ph == 1) ? Bl : Bh;
    int k0 = kt << 6;
    __syncthreads();  // previous tile's reads complete
#pragma unroll
    for (int c = 0; c < 4; ++c) {
      int off = off_ + (c << 12);     // 0..16383, 16B per lane
      int row = off >> 7;             // tile row
      int cole = (off & 127) >> 1;    // bf16 col within BK
      const unsigned short* ga = Ap + (size_t)(m0 + row) * K + k0 + cole;
      const unsigned short* gb = Bp + (size_t)(n0 + row) * K + k0 + cole;
      __builtin_amdgcn_global_load_lds(
          (const __attribute__((address_space(1))) void*)ga,
          (__attribute__((address_space(3))) void*)((char*)As + off), 16, 0, 0);
      __builtin_amdgcn_global_load_lds(
          (const __attribute__((address_space(1))) void*)gb,
          (__attribute__((address_space(3))) void*)((char*)Bs + off), 16, 0, 0);
    }
    __syncthreads();  // staging visible (compiler drains vmcnt before barrier)
#pragma unroll
    for (int ks = 0; ks < 2; ++ks) {
      short8v af[4], bf[4];
#pragma unroll
      for (int f = 0; f < 4; ++f) {
        int arow = wr * 64 + f * 16 + l15;
        int brow = wc * 64 + f * 16 + l15;
        int colb = ks * 64 + lk * 16;  // byte offset within 128B row
        af[f] = *(const short8v*)((const char*)As + arow * 128 + colb);
        bf[f] = *(const short8v*)((const char*)Bs + brow * 128 + colb);
      }
#pragma unroll
      for (int fm = 0; fm < 4; ++fm)
#pragma unroll
        for (int fn = 0; fn < 4; ++fn)
          acc[fm][fn] = __builtin_amdgcn_mfma_f32_16x16x32_bf16(af[fm], bf[fn], acc[fm][fn], 0, 0, 0);
    }
  }
#pragma unroll
  for (int fm = 0; fm < 4; ++fm) {
    int rbase = m0 + wr * 64 + fm * 16 + lk * 4;
#pragma unroll
    for (int j = 0; j < 4; ++j) {
      float* cp = C + (size_t)(rbase + j) * N + n0 + wc * 64 + l15;
#pragma unroll
      for (int fn = 0; fn < 4; ++fn) cp[fn * 16] = acc[fm][fn][j];
    }
  }
}

// ---------------- fp32 NT GEMM with K-slice (for K/V projections) ----------------
__global__ __launch_bounds__(256) void gemm_nt_part_k(const float* __restrict__ A,
                                                      const float* __restrict__ Bm,
                                                      float* __restrict__ Cpart,
                                                      int M, int N, int K, int kslice) {
  __shared__ float As[16 * 132];
  __shared__ float Bs[16 * 132];
  int tid = threadIdx.x;
  int tx = tid & 15, ty = tid >> 4;
  int m0 = blockIdx.y * 128, n0 = blockIdx.x * 128;
  float* C = Cpart + (size_t)blockIdx.z * M * N;
  int kbeg = blockIdx.z * kslice, kend = kbeg + kslice;
  int lr = tid >> 1, lc = (tid & 1) * 8;
  const float* Ap = A + (long)(m0 + lr) * K + lc;
  const float* Bp = Bm + (long)(n0 + lr) * K + lc;
  float acc[8][8];
#pragma unroll
  for (int i = 0; i < 8; i++)
#pragma unroll
    for (int j = 0; j < 8; j++) acc[i][j] = 0.f;

  for (int k0 = kbeg; k0 < kend; k0 += 16) {
    float4 a0 = *(const float4*)(Ap + k0);
    float4 a1 = *(const float4*)(Ap + k0 + 4);
    float4 b0 = *(const float4*)(Bp + k0);
    float4 b1 = *(const float4*)(Bp + k0 + 4);
    As[(lc + 0) * 132 + lr] = a0.x;
    As[(lc + 1) * 132 + lr] = a0.y;
    As[(lc + 2) * 132 + lr] = a0.z;
    As[(lc + 3) * 132 + lr] = a0.w;
    As[(lc + 4) * 132 + lr] = a1.x;
    As[(lc + 5) * 132 + lr] = a1.y;
    As[(lc + 6) * 132 + lr] = a1.z;
    As[(lc + 7) * 132 + lr] = a1.w;
    Bs[(lc + 0) * 132 + lr] = b0.x;
    Bs[(lc + 1) * 132 + lr] = b0.y;
    Bs[(lc + 2) * 132 + lr] = b0.z;
    Bs[(lc + 3) * 132 + lr] = b0.w;
    Bs[(lc + 4) * 132 + lr] = b1.x;
    Bs[(lc + 5) * 132 + lr] = b1.y;
    Bs[(lc + 6) * 132 + lr] = b1.z;
    Bs[(lc + 7) * 132 + lr] = b1.w;
    __syncthreads();
#pragma unroll
    for (int kk = 0; kk < 16; kk++) {
      float4 aa0 = *(const float4*)&As[kk * 132 + ty * 4];
      float4 aa1 = *(const float4*)&As[kk * 132 + 64 + ty * 4];
      float4 bb0 = *(const float4*)&Bs[kk * 132 + tx * 4];
      float4 bb1 = *(const float4*)&Bs[kk * 132 + 64 + tx * 4];
      float av[8] = {aa0.x, aa0.y, aa0.z, aa0.w, aa1.x, aa1.y, aa1.z, aa1.w};
      float bv[8] = {bb0.x, bb0.y, bb0.z, bb0.w, bb1.x, bb1.y, bb1.z, bb1.w};
#pragma unroll
      for (int i = 0; i < 8; i++)
#pragma unroll
        for (int j = 0; j < 8; j++) acc[i][j] += av[i] * bv[j];
    }
    __syncthreads();
  }
#pragma unroll
  for (int i = 0; i < 8; i++) {
    int r = m0 + ((i < 4) ? (ty * 4 + i) : (64 + ty * 4 + (i - 4)));
    float* cp = C + (long)r * N + n0;
    *(float4*)(cp + tx * 4) = make_float4(acc[i][0], acc[i][1], acc[i][2], acc[i][3]);
    *(float4*)(cp + 64 + tx * 4) = make_float4(acc[i][4], acc[i][5], acc[i][6], acc[i][7]);
  }
}

__global__ void reduce4_k(const float* __restrict__ p, float* __restrict__ dst, int n) {
  int i = blockIdx.x * 256 + threadIdx.x;
  if (i < n) dst[i] = (p[i] + p[i + n]) + (p[i + 2 * n] + p[i + 3 * n]);
}

// ---------------- RoPE / KV transform / quant ----------------

__global__ void rope_apply_k(float* buf, const float* __restrict__ ct,
                             const float* __restrict__ st, int heads, int total) {
  int idx = blockIdx.x * 256 + threadIdx.x;
  if (idx >= total) return;
  int j = idx & 63;
  int hh = (idx >> 6) % heads;
  int row = idx / (64 * heads);
  int t = row & (SS - 1);
  float c = ct[t * 64 + j], s = st[t * 64 + j];
  float* p = buf + ((long)row * heads + hh) * 128;
  float x0 = p[j], x1 = p[j + 64];
  p[j] = x0 * c - x1 * s;
  p[j + 64] = x1 * c + x0 * s;
}

__global__ __launch_bounds__(128) void kv_transform_k(float* kb, float* vb,
                                                      const float* __restrict__ mk,
                                                      const float* __restrict__ mv,
                                                      unsigned* mmx) {
  int which = blockIdx.y;
  float* buf = which ? vb : kb;
  const float* M = which ? mv : mk;
  __shared__ float rowb[128];
  __shared__ float red[128];
  int tid = threadIdx.x;
  float vmin = 3.4e38f, vmax = -3.4e38f;
  int r0 = blockIdx.x * 128;
  for (int ri = 0; ri < 128; ri++) {
    long row = r0 + ri;
    __syncthreads();
    rowb[tid] = buf[row * 128 + tid];
    __syncthreads();
    float acc = 0.f;
#pragma unroll 8
    for (int a = 0; a < 128; a++) acc += rowb[a] * M[a * 128 + tid];
    buf[row * 128 + tid] = acc;
    vmin = fminf(vmin, acc);
    vmax = fmaxf(vmax, acc);
  }
  red[tid] = vmin;
  __syncthreads();
  for (int s2 = 64; s2 > 0; s2 >>= 1) {
    if (tid < s2) red[tid] = fminf(red[tid], red[tid + s2]);
    __syncthreads();
  }
  if (tid == 0) atomicMin(&mmx[which * 2 + 0], encf(red[0]));
  __syncthreads();
  red[tid] = vmax;
  __syncthreads();
  for (int s2 = 64; s2 > 0; s2 >>= 1) {
    if (tid < s2) red[tid] = fmaxf(red[tid], red[tid + s2]);
    __syncthreads();
  }
  if (tid == 0) atomicMax(&mmx[which * 2 + 1], encf(red[0]));
}

__global__ void quant_k(float* kb, float* vb, const unsigned* __restrict__ mmx) {
  int idx = blockIdx.x * 256 + threadIdx.x;
  int which = idx >> 20;
  float* buf = which ? vb : kb;
  int i = idx & 1048575;
  float fmin = decf(mmx[which * 2 + 0]);
  float fmax = decf(mmx[which * 2 + 1]);
  float sc = (fmax - fmin) / 255.0f;
  float t = buf[i];
  float qv = rintf((t - fmin) / sc);
  qv = fminf(fmaxf(qv, 0.0f), 255.0f);
  buf[i] = qv * sc + fmin;
}

// ---------------- windowed sigmoid attention (unchanged) ----------------
__global__ __launch_bounds__(256) void attn_k(const float* q, const float* kq,
                                              const float* vq, float* outp) {
  __shared__ float Qs[32 * 129];
  __shared__ float Ks[32 * 129];
  __shared__ float Vs[32 * 132];
  __shared__ float Ps[32 * 33];
  __shared__ float rsum[32];
  int tid = threadIdx.x;
  int b = blockIdx.y >> 4;
  int h = blockIdx.y & 15;
  int t0 = blockIdx.x * 32;
  int wa = t0 >> 8;

  for (int i = tid; i < 4096; i += 256) {
    int r = i >> 7, d = i & 127;
    Qs[r * 129 + d] = q[((long)(b * SS + t0 + r) * NHEADS + h) * HDIM + d];
  }

  int rP = tid >> 3;
  int c0 = (tid & 7) * 16;
  int cS = tid & 31;
  int rg = (tid >> 5) * 4;
  float alpha = (float)((t0 + rP) & 255) * (1.0f / 255.0f);

  float accOut[16];
#pragma unroll
  for (int j = 0; j < 16; j++) accOut[j] = 0.f;

  for (int pass = 0; pass < 2; pass++) {
    int wsS, wsE;
    if (pass == 0) {
      if (wa == 0) continue;
      wsS = wa * 256 - 256;
      wsE = wsS + 512;
    } else {
      wsS = wa * 256;
      wsE = wsS + 512;
      if (wsE > SS) wsE = SS;
    }
    if (tid < 32) rsum[tid] = 0.f;
    float acc[16];
#pragma unroll
    for (int j = 0; j < 16; j++) acc[j] = 0.f;
    __syncthreads();
    for (int k0 = wsS; k0 < wsE; k0 += 32) {
      for (int i = tid; i < 4096; i += 256) {
        int r = i >> 7, d = i & 127;
        long grow = (long)(b * SS + k0 + r) * HDIM + d;
        Ks[r * 129 + d] = kq[grow];
        Vs[r * 132 + d] = vq[grow];
      }
      __syncthreads();
      {
        float s0 = 0.f, s1 = 0.f, s2 = 0.f, s3 = 0.f;
        const float* kp = &Ks[cS * 129];
        const float* q0 = &Qs[(rg + 0) * 129];
        const float* q1 = &Qs[(rg + 1) * 129];
        const float* q2 = &Qs[(rg + 2) * 129];
        const float* q3 = &Qs[(rg + 3) * 129];
#pragma unroll 8
        for (int kd = 0; kd < 128; kd++) {
          float kv = kp[kd];
          s0 += q0[kd] * kv;
          s1 += q1[kd] * kv;
          s2 += q2[kd] * kv;
          s3 += q3[kd] * kv;
        }
        Ps[(rg + 0) * 33 + cS] = sigf(s0 * ATT_SCALE);
        Ps[(rg + 1) * 33 + cS] = sigf(s1 * ATT_SCALE);
        Ps[(rg + 2) * 33 + cS] = sigf(s2 * ATT_SCALE);
        Ps[(rg + 3) * 33 + cS] = sigf(s3 * ATT_SCALE);
      }
      __syncthreads();
      if (tid < 32) {
        float sm = 0.f;
#pragma unroll 8
        for (int c = 0; c < 32; c++) sm += Ps[tid * 33 + c];
        rsum[tid] += sm;
      }
#pragma unroll 4
      for (int k = 0; k < 32; k++) {
        float p = Ps[rP * 33 + k];
        const float* vp = &Vs[k * 132 + c0];
        float4 v0 = *(const float4*)(vp + 0);
        float4 v1 = *(const float4*)(vp + 4);
        float4 v2 = *(const float4*)(vp + 8);
        float4 v3 = *(const float4*)(vp + 12);
        acc[0] += p * v0.x;
        acc[1] += p * v0.y;
        acc[2] += p * v0.z;
        acc[3] += p * v0.w;
        acc[4] += p * v1.x;
        acc[5] += p * v1.y;
        acc[6] += p * v1.z;
        acc[7] += p * v1.w;
        acc[8] += p * v2.x;
        acc[9] += p * v2.y;
        acc[10] += p * v2.z;
        acc[11] += p * v2.w;
        acc[12] += p * v3.x;
        acc[13] += p * v3.y;
        acc[14] += p * v3.z;
        acc[15] += p * v3.w;
      }
      __syncthreads();
    }
    float inv = 1.0f / (rsum[rP] + 1e-8f);
    float w = (pass == 0) ? (1.0f - alpha) : ((wa == 0) ? 1.0f : alpha);
#pragma unroll
    for (int j = 0; j < 16; j++) accOut[j] += w * acc[j] * inv;
    __syncthreads();
  }
#pragma unroll
  for (int j = 0; j < 16; j++)
    outp[((long)(b * SS + t0 + rP) * NHEADS + h) * HDIM + c0 + j] = accOut[j];
}

extern "C" void kernel_launch(void* const* d_in, const int* in_sizes, int n_in,
                              void* d_out, int out_size, void* d_ws, size_t ws_size,
                              hipStream_t stream) {
  const float* x = (const float*)d_in[0];
  const float* wq = (const float*)d_in[1];
  const float* wk = (const float*)d_in[2];
  const float* wv = (const float*)d_in[3];
  const float* wo = (const float*)d_in[4];
  const float* kcw = (const float*)d_in[5];
  const float* vcw = (const float*)d_in[6];
  const float* kdw = (const float*)d_in[7];
  const float* vdw = (const float*)d_in[8];
  float* out = (float*)d_out;

  const long QN = (long)BSROWS * HIDDEN;   // 16,777,216
  const long KVN = (long)BSROWS * HDIM;    // 1,048,576

  float* q = (float*)d_ws;                 // QN floats
  float* kb = q + QN;                      // KVN
  float* vb = kb + KVN;                    // KVN
  float* kpart = vb + KVN;                 // 4*KVN
  float* vpart = kpart + 4 * KVN;          // 4*KVN
  float* ct = vpart + 4 * KVN;             // SS*64
  float* st = ct + SS * 64;
  float* mk = st + SS * 64;
  float* mv = mk + 128 * 128;
  unsigned* mmx = (unsigned*)(mv + 128 * 128);
  unsigned short* xh = (unsigned short*)(mmx + 16);  // QN bf16
  unsigned short* xl = xh + QN;                      // QN
  unsigned short* wqh = xl + QN;                     // 4.2M each
  unsigned short* wql = wqh + (long)HIDDEN * HIDDEN;
  unsigned short* woh = wql + (long)HIDDEN * HIDDEN;
  unsigned short* wol = woh + (long)HIDDEN * HIDDEN;

  rope_tables_k<<<SS, 64, 0, stream>>>(ct, st);
  build_m_k<<<dim3(128, 2), 128, 0, stream>>>(kcw, kdw, vcw, vdw, mk, mv);

  // splits
  split_bf16_k<<<2048, 256, 0, stream>>>(x, xh, xl, (int)(QN / 4));
  split_bf16_k<<<512, 256, 0, stream>>>(wq, wqh, wql, HIDDEN * HIDDEN / 4);
  split_bf16_k<<<512, 256, 0, stream>>>(wo, woh, wol, HIDDEN * HIDDEN / 4);

  // Q = x @ wq^T  (bf16-split MFMA)
  gemm_split_mfma_k<<<dim3(HIDDEN / 128, BSROWS / 128), 256, 0, stream>>>(xh, xl, wqh, wql, q);

  // K,V projections: fp32 split-K (4 slices) + deterministic reduce
  gemm_nt_part_k<<<dim3(1, BSROWS / 128, 4), 256, 0, stream>>>(x, wk, kpart, BSROWS, HDIM, HIDDEN, HIDDEN / 4);
  gemm_nt_part_k<<<dim3(1, BSROWS / 128, 4), 256, 0, stream>>>(x, wv, vpart, BSROWS, HDIM, HIDDEN, HIDDEN / 4);
  reduce4_k<<<(int)(KVN / 256), 256, 0, stream>>>(kpart, kb, (int)KVN);
  reduce4_k<<<(int)(KVN / 256), 256, 0, stream>>>(vpart, vb, (int)KVN);

  // RoPE
  rope_apply_k<<<(BSROWS * NHEADS * 64) / 256, 256, 0, stream>>>(q, ct, st, NHEADS, BSROWS * NHEADS * 64);
  rope_apply_k<<<(BSROWS * 64) / 256, 256, 0, stream>>>(kb, ct, st, 1, BSROWS * 64);

  // KV low-rank transform + minmax + quant
  mm_init_k<<<1, 64, 0, stream>>>(mmx);
  kv_transform_k<<<dim3(BSROWS / 128, 2), 128, 0, stream>>>(kb, vb, mk, mv, mmx);
  quant_k<<<(int)(2 * KVN / 256), 256, 0, stream>>>(kb, vb, mmx);

  // attention (in-place into q)
  attn_k<<<dim3(SS / 32, BB * NHEADS), 256, 0, stream>>>(q, kb, vb, q);

  // split attention output, then out = attn @ wo^T (bf16-split MFMA)
  split_bf16_k<<<2048, 256, 0, stream>>>(q, xh, xl, (int)(QN / 4));
  gemm_split_mfma_k<<<dim3(HIDDEN / 128, BSROWS / 128), 256, 0, stream>>>(xh, xl, woh, wol, out);
}

// Round 3
// 1233.373 us; speedup vs baseline: 3.9455x; 2.9387x over previous
//
#include <hip/hip_runtime.h>
#include <hip/hip_bf16.h>
#include <math.h>

#define BB 4
#define SS 2048
#define HIDDEN 2048
#define NHEADS 16
#define HDIM 128
#define BSROWS (BB * SS)
#define ATT_SCALE 0.08838834764831845f

typedef __attribute__((ext_vector_type(8))) short short8v;
typedef __attribute__((ext_vector_type(4))) float f32x4;

static __device__ __forceinline__ unsigned encf(float x) {
  unsigned b = __float_as_uint(x);
  return (b & 0x80000000u) ? ~b : (b | 0x80000000u);
}
static __device__ __forceinline__ float decf(unsigned k) {
  unsigned b = (k & 0x80000000u) ? (k ^ 0x80000000u) : ~k;
  return __uint_as_float(b);
}
static __device__ __forceinline__ unsigned short f2bf(float f) {
  unsigned u = __float_as_uint(f);
  u += 0x7FFFu + ((u >> 16) & 1u);  // RNE
  return (unsigned short)(u >> 16);
}
static __device__ __forceinline__ float bf2f(unsigned short h) {
  return __uint_as_float(((unsigned)h) << 16);
}

// ---------------- small setup kernels ----------------

__global__ void rope_tables_k(float* __restrict__ ct, float* __restrict__ st) {
  int t = blockIdx.x;
  int d = threadIdx.x;  // 0..63
  float inv = powf(10000.0f, -(float)d * (1.0f / 64.0f));
  float a = (float)t * inv;
  ct[t * 64 + d] = cosf(a);
  st[t * 64 + d] = sinf(a);
}

__global__ void build_m_k(const float* __restrict__ kc, const float* __restrict__ kdw,
                          const float* __restrict__ vc, const float* __restrict__ vdw,
                          float* __restrict__ mk, float* __restrict__ mv) {
  int a = blockIdx.x;
  int c = threadIdx.x;
  const float* cw = blockIdx.y ? vc : kc;
  const float* dw = blockIdx.y ? vdw : kdw;
  float* m = blockIdx.y ? mv : mk;
  float acc = 0.f;
#pragma unroll
  for (int mm = 0; mm < 32; mm++) acc += cw[mm * 128 + a] * dw[c * 32 + mm];
  m[a * 128 + c] = acc;
}

__global__ void mm_init_k(unsigned* mmx) {
  int i = threadIdx.x;
  if (i < 4) mmx[i] = (i & 1) ? 0u : 0xFFFFFFFFu;
}

// split fp32 -> bf16 hi + bf16 lo (residual)
__global__ void split_bf16_k(const float* __restrict__ src, unsigned short* __restrict__ hi,
                             unsigned short* __restrict__ lo, int n4) {
  int i = blockIdx.x * 256 + threadIdx.x;
  int stride = gridDim.x * 256;
  for (; i < n4; i += stride) {
    float4 v = ((const float4*)src)[i];
    unsigned short h0 = f2bf(v.x), h1 = f2bf(v.y), h2 = f2bf(v.z), h3 = f2bf(v.w);
    unsigned short l0 = f2bf(v.x - bf2f(h0));
    unsigned short l1 = f2bf(v.y - bf2f(h1));
    unsigned short l2 = f2bf(v.z - bf2f(h2));
    unsigned short l3 = f2bf(v.w - bf2f(h3));
    ((ushort4*)hi)[i] = make_ushort4(h0, h1, h2, h3);
    ((ushort4*)lo)[i] = make_ushort4(l0, l1, l2, l3);
  }
}

// ---------------- bf16-split MFMA GEMM ----------------
// A: [8192][2048] bf16 rm (hi/lo). B: [N<=2304][2048] bf16 rm.
// C = A.B^T fp32: cols <2048 -> Cq (ld 2048); cols >=2048 -> Ckv (ld 256).
__global__ __launch_bounds__(256) void gemm_split_mfma_k(
    const unsigned short* __restrict__ Ah, const unsigned short* __restrict__ Al,
    const unsigned short* __restrict__ Bh, const unsigned short* __restrict__ Bl,
    float* __restrict__ Cq, float* __restrict__ Ckv) {
  const int K = 2048;
  __shared__ unsigned short As[128 * 64];
  __shared__ unsigned short Bs[128 * 64];
  int tid = threadIdx.x;
  int lane = tid & 63, wid = tid >> 6;
  int wr = wid >> 1, wc = wid & 1;
  int m0 = blockIdx.y * 128, n0 = blockIdx.x * 128;

  f32x4 acc[4][4] = {};

  int off_ = (wid << 10) + (lane << 4);
  int l15 = lane & 15, lk = lane >> 4;

  for (int t = 0; t < 96; ++t) {
    int ph = t >> 5;
    int kt = t & 31;
    const unsigned short* Ap = (ph == 2) ? Al : Ah;
    const unsigned short* Bp = (ph == 1) ? Bl : Bh;
    int k0 = kt << 6;
    __syncthreads();
#pragma unroll
    for (int c = 0; c < 4; ++c) {
      int off = off_ + (c << 12);
      int row = off >> 7;
      int cole = (off & 127) >> 1;
      const unsigned short* ga = Ap + (size_t)(m0 + row) * K + k0 + cole;
      const unsigned short* gb = Bp + (size_t)(n0 + row) * K + k0 + cole;
      __builtin_amdgcn_global_load_lds(
          (const __attribute__((address_space(1))) void*)ga,
          (__attribute__((address_space(3))) void*)((char*)As + off), 16, 0, 0);
      __builtin_amdgcn_global_load_lds(
          (const __attribute__((address_space(1))) void*)gb,
          (__attribute__((address_space(3))) void*)((char*)Bs + off), 16, 0, 0);
    }
    __syncthreads();
#pragma unroll
    for (int ks = 0; ks < 2; ++ks) {
      short8v af[4], bf[4];
#pragma unroll
      for (int f = 0; f < 4; ++f) {
        int arow = wr * 64 + f * 16 + l15;
        int brow = wc * 64 + f * 16 + l15;
        int colb = ks * 64 + lk * 16;
        af[f] = *(const short8v*)((const char*)As + arow * 128 + colb);
        bf[f] = *(const short8v*)((const char*)Bs + brow * 128 + colb);
      }
#pragma unroll
      for (int fm = 0; fm < 4; ++fm)
#pragma unroll
        for (int fn = 0; fn < 4; ++fn)
          acc[fm][fn] = __builtin_amdgcn_mfma_f32_16x16x32_bf16(af[fm], bf[fn], acc[fm][fn], 0, 0, 0);
    }
  }
  bool iskv = (n0 >= 2048);
#pragma unroll
  for (int fm = 0; fm < 4; ++fm) {
#pragma unroll
    for (int j = 0; j < 4; ++j) {
      int row = m0 + wr * 64 + fm * 16 + lk * 4 + j;
#pragma unroll
      for (int fn = 0; fn < 4; ++fn) {
        int col = n0 + wc * 64 + fn * 16 + l15;
        if (!iskv)
          Cq[(size_t)row * 2048 + col] = acc[fm][fn][j];
        else
          Ckv[(size_t)row * 256 + (col - 2048)] = acc[fm][fn][j];
      }
    }
  }
}

// ---------------- RoPE ----------------

__global__ void rope_apply_k(float* buf, const float* __restrict__ ct,
                             const float* __restrict__ st, int heads, int total) {
  int idx = blockIdx.x * 256 + threadIdx.x;
  if (idx >= total) return;
  int j = idx & 63;
  int hh = (idx >> 6) % heads;
  int row = idx / (64 * heads);
  int t = row & (SS - 1);
  float c = ct[t * 64 + j], s = st[t * 64 + j];
  float* p = buf + ((long)row * heads + hh) * 128;
  float x0 = p[j], x1 = p[j + 64];
  p[j] = x0 * c - x1 * s;
  p[j + 64] = x1 * c + x0 * s;
}

// rope only the K half of kvb [row][256] (cols 0..127)
__global__ void rope_kv_k(float* kvb, const float* __restrict__ ct,
                          const float* __restrict__ st, int total) {
  int idx = blockIdx.x * 256 + threadIdx.x;
  if (idx >= total) return;
  int j = idx & 63;
  int row = idx >> 6;
  int t = row & (SS - 1);
  float c = ct[t * 64 + j], s = st[t * 64 + j];
  float* p = kvb + (size_t)row * 256;
  float x0 = p[j], x1 = p[j + 64];
  p[j] = x0 * c - x1 * s;
  p[j + 64] = x1 * c + x0 * s;
}

// ---------------- KV transform + minmax ----------------
// kvb [BSROWS][256]: cols 0..127 = K, 128..255 = V. In-place row @ M.
__global__ __launch_bounds__(128) void kv_transform_k(float* kvb,
                                                      const float* __restrict__ mk,
                                                      const float* __restrict__ mv,
                                                      unsigned* mmx) {
  int which = blockIdx.y;
  float* base = kvb + which * 128;
  const float* M = which ? mv : mk;
  __shared__ float rowb[128];
  __shared__ float red[128];
  int tid = threadIdx.x;
  float vmin = 3.4e38f, vmax = -3.4e38f;
  int r0 = blockIdx.x * 64;
  for (int ri = 0; ri < 64; ri++) {
    size_t row = r0 + ri;
    __syncthreads();
    rowb[tid] = base[row * 256 + tid];
    __syncthreads();
    float acc = 0.f;
#pragma unroll 8
    for (int a = 0; a < 128; a++) acc += rowb[a] * M[a * 128 + tid];
    base[row * 256 + tid] = acc;
    vmin = fminf(vmin, acc);
    vmax = fmaxf(vmax, acc);
  }
  red[tid] = vmin;
  __syncthreads();
  for (int s2 = 64; s2 > 0; s2 >>= 1) {
    if (tid < s2) red[tid] = fminf(red[tid], red[tid + s2]);
    __syncthreads();
  }
  if (tid == 0) atomicMin(&mmx[which * 2 + 0], encf(red[0]));
  __syncthreads();
  red[tid] = vmax;
  __syncthreads();
  for (int s2 = 64; s2 > 0; s2 >>= 1) {
    if (tid < s2) red[tid] = fmaxf(red[tid], red[tid + s2]);
    __syncthreads();
  }
  if (tid == 0) atomicMax(&mmx[which * 2 + 1], encf(red[0]));
}

// K codes: qkc[b][s][128] bf16 integers
__global__ void quant_k_codes_k(const float* __restrict__ kvb,
                                unsigned short* __restrict__ qkc,
                                const unsigned* __restrict__ mmx) {
  int i = blockIdx.x * 256 + threadIdx.x;  // 0..BSROWS*128-1
  float mn = decf(mmx[0]);
  float sc = (decf(mmx[1]) - mn) * (1.f / 255.f);
  int row = i >> 7, d = i & 127;
  float v = kvb[(size_t)row * 256 + d];
  float qv = fminf(fmaxf(rintf((v - mn) / sc), 0.f), 255.f);
  qkc[i] = f2bf(qv);
}

// V codes transposed: qvtc[b][d=128][s=2048] bf16 integers
__global__ __launch_bounds__(256) void quant_vt_k(const float* __restrict__ kvb,
                                                  unsigned short* __restrict__ qvtc,
                                                  const unsigned* __restrict__ mmx) {
  int b = blockIdx.y;
  int s0 = blockIdx.x * 64;
  __shared__ unsigned short tile[128 * 72];
  float mn = decf(mmx[2]);
  float sc = (decf(mmx[3]) - mn) * (1.f / 255.f);
  for (int i = threadIdx.x; i < 8192; i += 256) {
    int sl = i >> 7, d = i & 127;
    float v = kvb[((size_t)(b * SS + s0 + sl)) * 256 + 128 + d];
    float qv = fminf(fmaxf(rintf((v - mn) / sc), 0.f), 255.f);
    tile[d * 72 + sl] = f2bf(qv);
  }
  __syncthreads();
  int d = threadIdx.x >> 1, hf = threadIdx.x & 1;
  unsigned short* dst = qvtc + (size_t)(b * 128 + d) * 2048 + s0 + hf * 32;
  const unsigned short* srcp = &tile[d * 72 + hf * 32];
#pragma unroll
  for (int u = 0; u < 4; ++u)
    *(short8v*)(dst + u * 8) = *(const short8v*)(srcp + u * 8);
}

// ---------------- MFMA windowed sigmoid attention ----------------
// block: 256 thr = 4 waves; 64 q-rows of one (b,h); wave w owns rows 16w..16w+15.
// Segments: A=[base-256,base) prev-only, B=[base,base+256) shared, C=[base+256,base+512) cur-only.
__global__ __launch_bounds__(256) void attn_mfma_k(
    const float* __restrict__ qbuf, const unsigned short* __restrict__ qkc,
    const unsigned short* __restrict__ qvtc, const unsigned* __restrict__ mmx,
    float* __restrict__ outp) {
  __shared__ unsigned short Ks[64 * 128];   // [key][d] swizzled, 16KB
  __shared__ unsigned short Vt[128 * 64];   // [d][key] swizzled, 16KB
  __shared__ unsigned short Pl[64 * 64];    // [qrow][key] swizzled, 8KB
  __shared__ float sumQs[64];
  int tid = threadIdx.x;
  int lane = tid & 63, w = tid >> 6;
  int l15 = lane & 15, lg = lane >> 4;
  int swk = (l15 & 7) << 4;
  int b = blockIdx.y >> 4, h = blockIdx.y & 15;
  int t0 = blockIdx.x * 64;
  int wa = t0 >> 8;

  float mnk = decf(mmx[0]), sck = (decf(mmx[1]) - mnk) * (1.f / 255.f);
  float mnv = decf(mmx[2]), scv = (decf(mmx[3]) - mnv) * (1.f / 255.f);

  // ---- Q fragments (bf16) + row sums ----
  short8v qf[4];
  {
    const float* qrow = qbuf + ((size_t)(b * SS + t0 + w * 16 + l15) * NHEADS + h) * HDIM;
    float sq = 0.f;
#pragma unroll
    for (int kk = 0; kk < 4; ++kk) {
      float4 v0 = *(const float4*)(qrow + kk * 32 + lg * 8);
      float4 v1 = *(const float4*)(qrow + kk * 32 + lg * 8 + 4);
      sq += v0.x + v0.y + v0.z + v0.w + v1.x + v1.y + v1.z + v1.w;
      short8v t;
      t[0] = (short)f2bf(v0.x); t[1] = (short)f2bf(v0.y);
      t[2] = (short)f2bf(v0.z); t[3] = (short)f2bf(v0.w);
      t[4] = (short)f2bf(v1.x); t[5] = (short)f2bf(v1.y);
      t[6] = (short)f2bf(v1.z); t[7] = (short)f2bf(v1.w);
      qf[kk] = t;
    }
    sq += __shfl_xor(sq, 16);
    sq += __shfl_xor(sq, 32);
    if (lane < 16) sumQs[w * 16 + l15] = sq;
  }
  float squ[4];
#pragma unroll
  for (int j = 0; j < 4; ++j) squ[j] = 0.f;  // loaded after first barrier

  f32x4 zz = {0.f, 0.f, 0.f, 0.f};
  f32x4 accA[8], accB[8], accC[8];
#pragma unroll
  for (int i = 0; i < 8; ++i) { accA[i] = zz; accB[i] = zz; accC[i] = zz; }
  float rsA[4] = {0, 0, 0, 0}, rsB[4] = {0, 0, 0, 0}, rsC[4] = {0, 0, 0, 0};
  int base = wa * 256;
  bool squload = false;

#define CHUNK(K0, ACC, RS)                                                          \
  do {                                                                              \
    int k0_ = (K0);                                                                 \
    __syncthreads();                                                                \
    {                                                                               \
      const char* kb_ = (const char*)qkc + ((size_t)b * SS + k0_) * 256;            \
      const char* vb_ = (const char*)qvtc + (size_t)b * 524288 + (size_t)k0_ * 2;   \
      _Pragma("unroll") for (int i_ = 0; i_ < 4; ++i_) {                            \
        int L_ = w * 4096 + i_ * 1024 + lane * 16;                                  \
        int kr_ = L_ >> 8;                                                          \
        int kd_ = (L_ & 255) ^ ((kr_ & 7) << 4);                                    \
        __builtin_amdgcn_global_load_lds(                                           \
            (const __attribute__((address_space(1))) void*)(kb_ + kr_ * 256 + kd_), \
            (__attribute__((address_space(3))) void*)((char*)Ks + L_), 16, 0, 0);   \
        int vr_ = L_ >> 7;                                                          \
        int vd_ = (L_ & 127) ^ ((vr_ & 7) << 4);                                    \
        __builtin_amdgcn_global_load_lds(                                           \
            (const __attribute__((address_space(1))) void*)(vb_ + vr_ * 4096 + vd_),\
            (__attribute__((address_space(3))) void*)((char*)Vt + L_), 16, 0, 0);   \
      }                                                                             \
    }                                                                               \
    __syncthreads();                                                                \
    if (!squload) {                                                                 \
      _Pragma("unroll") for (int j_ = 0; j_ < 4; ++j_)                              \
          squ[j_] = sumQs[w * 16 + lg * 4 + j_];                                    \
      squload = true;                                                               \
    }                                                                               \
    f32x4 sf0 = zz, sf1 = zz, sf2 = zz, sf3 = zz;                                   \
    _Pragma("unroll") for (int kk_ = 0; kk_ < 4; ++kk_) {                           \
      int cb_ = (kk_ * 64 + lg * 16) ^ swk;                                         \
      short8v k0f = *(const short8v*)((const char*)Ks + (0 * 16 + l15) * 256 + cb_);\
      short8v k1f = *(const short8v*)((const char*)Ks + (1 * 16 + l15) * 256 + cb_);\
      short8v k2f = *(const short8v*)((const char*)Ks + (2 * 16 + l15) * 256 + cb_);\
      short8v k3f = *(const short8v*)((const char*)Ks + (3 * 16 + l15) * 256 + cb_);\
      sf0 = __builtin_amdgcn_mfma_f32_16x16x32_bf16(qf[kk_], k0f, sf0, 0, 0, 0);    \
      sf1 = __builtin_amdgcn_mfma_f32_16x16x32_bf16(qf[kk_], k1f, sf1, 0, 0, 0);    \
      sf2 = __builtin_amdgcn_mfma_f32_16x16x32_bf16(qf[kk_], k2f, sf2, 0, 0, 0);    \
      sf3 = __builtin_amdgcn_mfma_f32_16x16x32_bf16(qf[kk_], k3f, sf3, 0, 0, 0);    \
    }                                                                               \
    float rsc_[4] = {0.f, 0.f, 0.f, 0.f};                                           \
    _Pragma("unroll") for (int nf_ = 0; nf_ < 4; ++nf_) {                           \
      f32x4 sv = (nf_ == 0) ? sf0 : (nf_ == 1) ? sf1 : (nf_ == 2) ? sf2 : sf3;      \
      _Pragma("unroll") for (int j_ = 0; j_ < 4; ++j_) {                            \
        float s_ = ATT_SCALE * (sck * sv[j_] + mnk * squ[j_]);                      \
        float p_ = 1.f / (1.f + __expf(-s_));                                       \
        rsc_[j_] += p_;                                                             \
        int prow_ = w * 16 + lg * 4 + j_;                                           \
        int paddr_ = prow_ * 128 + (((nf_ * 16 + l15) * 2) ^ ((prow_ & 7) << 4));   \
        *(unsigned short*)((char*)Pl + paddr_) = f2bf(p_);                          \
      }                                                                             \
    }                                                                               \
    _Pragma("unroll") for (int j_ = 0; j_ < 4; ++j_) {                              \
      rsc_[j_] += __shfl_xor(rsc_[j_], 1);                                          \
      rsc_[j_] += __shfl_xor(rsc_[j_], 2);                                          \
      rsc_[j_] += __shfl_xor(rsc_[j_], 4);                                          \
      rsc_[j_] += __shfl_xor(rsc_[j_], 8);                                          \
      RS[j_] += rsc_[j_];                                                           \
    }                                                                               \
    short8v pf0, pf1;                                                               \
    {                                                                               \
      int prow_ = w * 16 + l15;                                                     \
      pf0 = *(const short8v*)((const char*)Pl + prow_ * 128 + ((lg * 16) ^ swk));   \
      pf1 = *(const short8v*)((const char*)Pl + prow_ * 128 + ((64 + lg * 16) ^ swk)); \
    }                                                                               \
    _Pragma("unroll") for (int nf_ = 0; nf_ < 8; ++nf_) {                           \
      int vb0_ = (nf_ * 16 + l15) * 128 + ((lg * 16) ^ swk);                        \
      int vb1_ = (nf_ * 16 + l15) * 128 + ((64 + lg * 16) ^ swk);                   \
      short8v vf0 = *(const short8v*)((const char*)Vt + vb0_);                      \
      short8v vf1 = *(const short8v*)((const char*)Vt + vb1_);                      \
      ACC[nf_] = __builtin_amdgcn_mfma_f32_16x16x32_bf16(pf0, vf0, ACC[nf_], 0, 0, 0); \
      ACC[nf_] = __builtin_amdgcn_mfma_f32_16x16x32_bf16(pf1, vf1, ACC[nf_], 0, 0, 0); \
    }                                                                               \
  } while (0)

  if (wa > 0) {
    CHUNK(base - 256 + 0 * 64, accA, rsA);
    CHUNK(base - 256 + 1 * 64, accA, rsA);
    CHUNK(base - 256 + 2 * 64, accA, rsA);
    CHUNK(base - 256 + 3 * 64, accA, rsA);
  }
  {
    CHUNK(base + 0 * 64, accB, rsB);
    CHUNK(base + 1 * 64, accB, rsB);
    CHUNK(base + 2 * 64, accB, rsB);
    CHUNK(base + 3 * 64, accB, rsB);
  }
  if (wa < 7) {
    CHUNK(base + 256 + 0 * 64, accC, rsC);
    CHUNK(base + 256 + 1 * 64, accC, rsC);
    CHUNK(base + 256 + 2 * 64, accC, rsC);
    CHUNK(base + 256 + 3 * 64, accC, rsC);
  }
#undef CHUNK

  // ---- epilogue: normalize + blend + store ----
#pragma unroll
  for (int j = 0; j < 4; ++j) {
    int t = t0 + w * 16 + lg * 4 + j;
    float al = (float)(t & 255) * (1.f / 255.f);
    float r0 = rsA[j] + rsB[j], r1 = rsB[j] + rsC[j];
    float i0 = 1.f / (r0 + 1e-8f), i1 = 1.f / (r1 + 1e-8f);
    float w0 = (wa == 0) ? 0.f : (1.f - al);
    float w1 = (wa == 0) ? 1.f : al;
    float* orow = outp + ((size_t)(b * SS + t) * NHEADS + h) * HDIM;
#pragma unroll
    for (int nf = 0; nf < 8; ++nf) {
      float o0 = (scv * (accA[nf][j] + accB[nf][j]) + mnv * r0) * i0;
      float o1 = (scv * (accB[nf][j] + accC[nf][j]) + mnv * r1) * i1;
      orow[nf * 16 + l15] = w0 * o0 + w1 * o1;
    }
  }
}

extern "C" void kernel_launch(void* const* d_in, const int* in_sizes, int n_in,
                              void* d_out, int out_size, void* d_ws, size_t ws_size,
                              hipStream_t stream) {
  const float* x = (const float*)d_in[0];
  const float* wq = (const float*)d_in[1];
  const float* wk = (const float*)d_in[2];
  const float* wv = (const float*)d_in[3];
  const float* wo = (const float*)d_in[4];
  const float* kcw = (const float*)d_in[5];
  const float* vcw = (const float*)d_in[6];
  const float* kdw = (const float*)d_in[7];
  const float* vdw = (const float*)d_in[8];
  float* out = (float*)d_out;

  const size_t QN = (size_t)BSROWS * HIDDEN;   // 16,777,216
  const size_t KVN = (size_t)BSROWS * 256;     // 2,097,152 (kvb)

  float* q = (float*)d_ws;                     // QN
  float* kvb = q + QN;                         // KVN
  float* ct = kvb + KVN;                       // SS*64
  float* st = ct + SS * 64;
  float* mk = st + SS * 64;
  float* mv = mk + 128 * 128;
  unsigned* mmx = (unsigned*)(mv + 128 * 128); // 16 u32 slots (use 4)
  unsigned short* xh = (unsigned short*)(mmx + 16);    // QN
  unsigned short* xl = xh + QN;                        // QN
  unsigned short* wqkvh = xl + QN;                     // 2304*2048
  unsigned short* wqkvl = wqkvh + (size_t)2304 * 2048;
  unsigned short* woh = wqkvl + (size_t)2304 * 2048;   // 2048*2048
  unsigned short* wol = woh + (size_t)HIDDEN * HIDDEN;
  unsigned short* qkc = wol + (size_t)HIDDEN * HIDDEN; // BSROWS*128
  unsigned short* qvtc = qkc + (size_t)BSROWS * 128;   // BSROWS*128 (transposed per b)

  rope_tables_k<<<SS, 64, 0, stream>>>(ct, st);
  build_m_k<<<dim3(128, 2), 128, 0, stream>>>(kcw, kdw, vcw, vdw, mk, mv);

  // bf16 splits: x, [wq|wk|wv] concat rows, wo
  split_bf16_k<<<2048, 256, 0, stream>>>(x, xh, xl, (int)(QN / 4));
  split_bf16_k<<<512, 256, 0, stream>>>(wq, wqkvh, wqkvl, HIDDEN * HIDDEN / 4);
  split_bf16_k<<<256, 256, 0, stream>>>(wk, wqkvh + (size_t)2048 * 2048,
                                        wqkvl + (size_t)2048 * 2048, HDIM * HIDDEN / 4);
  split_bf16_k<<<256, 256, 0, stream>>>(wv, wqkvh + (size_t)2176 * 2048,
                                        wqkvl + (size_t)2176 * 2048, HDIM * HIDDEN / 4);
  split_bf16_k<<<512, 256, 0, stream>>>(wo, woh, wol, HIDDEN * HIDDEN / 4);

  // [Q|K|V] = x @ [wq|wk|wv]^T in one MFMA GEMM (N=2304)
  gemm_split_mfma_k<<<dim3(2304 / 128, BSROWS / 128), 256, 0, stream>>>(
      xh, xl, wqkvh, wqkvl, q, kvb);

  // RoPE on Q (16 heads) and K half of kvb
  rope_apply_k<<<(BSROWS * NHEADS * 64) / 256, 256, 0, stream>>>(q, ct, st, NHEADS,
                                                                 BSROWS * NHEADS * 64);
  rope_kv_k<<<(BSROWS * 64) / 256, 256, 0, stream>>>(kvb, ct, st, BSROWS * 64);

  // KV low-rank transform + global minmax, then quantize to codes
  mm_init_k<<<1, 64, 0, stream>>>(mmx);
  kv_transform_k<<<dim3(BSROWS / 64, 2), 128, 0, stream>>>(kvb, mk, mv, mmx);
  quant_k_codes_k<<<(BSROWS * 128) / 256, 256, 0, stream>>>(kvb, qkc, mmx);
  quant_vt_k<<<dim3(SS / 64, BB), 256, 0, stream>>>(kvb, qvtc, mmx);

  // MFMA attention (in-place into q)
  attn_mfma_k<<<dim3(SS / 64, BB * NHEADS), 256, 0, stream>>>(q, qkc, qvtc, mmx, q);

  // out = attn @ wo^T
  split_bf16_k<<<2048, 256, 0, stream>>>(q, xh, xl, (int)(QN / 4));
  gemm_split_mfma_k<<<dim3(HIDDEN / 128, BSROWS / 128), 256, 0, stream>>>(
      xh, xl, woh, wol, out, out);
}